// Round 8
// baseline (1314.278 us; speedup 1.0000x reference)
//
#include <hip/hip_runtime.h>
#include <hip/hip_bf16.h>
#include <math.h>

#define T_TOK 8192
#define H_DIM 1024
#define E_EXP 8
#define K_TOP 2
#define I_DIM 2048

typedef short bf16x8 __attribute__((ext_vector_type(8)));
typedef float f32x4 __attribute__((ext_vector_type(4)));

#define MFMA16(a, b, c) __builtin_amdgcn_mfma_f32_16x16x32_bf16((a), (b), (c), 0, 0, 0)

// LDS swizzle (units = shorts, row stride 32 shorts = 64B):
// chunk index F(r,kc) = (4r+kc) ^ (r&7)  [16B chunks]; SWZ = shorts offset.
#define SWZ(r, k) ((((r) * 32) + (k)) ^ (((r) & 7) << 3))

// inverse of F: given chunk c, the (row, kc) whose data must be stored there
__device__ __forceinline__ void dec_swz(int c, int& r, int& kc) {
    int q = c >> 2;
    r = (q & ~1) | ((q ^ (c >> 4)) & 1);
    kc = ((c ^ q ^ (c >> 4)) & 1) | ((c ^ q) & 2);
}

#define GLOAD16(G, L)                                                          \
    __builtin_amdgcn_global_load_lds(                                          \
        (const __attribute__((address_space(1))) void*)(G),                    \
        (__attribute__((address_space(3))) void*)(L), 16, 0, 0)

__device__ __forceinline__ unsigned short f2bf(float f) {
    unsigned u = __builtin_bit_cast(unsigned, f);
    u += 0x7fffu + ((u >> 16) & 1u);          // RNE
    return (unsigned short)(u >> 16);
}
__device__ __forceinline__ float bf2f(unsigned short s) {
    return __builtin_bit_cast(float, ((unsigned)s) << 16);
}
__device__ __forceinline__ void split4(float4 v, unsigned* hi, unsigned* lo) {
    unsigned short hx = f2bf(v.x), hy = f2bf(v.y), hz = f2bf(v.z), hw = f2bf(v.w);
    unsigned short lx = f2bf(v.x - bf2f(hx)), ly = f2bf(v.y - bf2f(hy));
    unsigned short lz = f2bf(v.z - bf2f(hz)), lw = f2bf(v.w - bf2f(hw));
    hi[0] = (unsigned)hx | ((unsigned)hy << 16);
    hi[1] = (unsigned)hz | ((unsigned)hw << 16);
    lo[0] = (unsigned)lx | ((unsigned)ly << 16);
    lo[1] = (unsigned)lz | ((unsigned)lw << 16);
}

// ---------------------------------------------------------------------------
__global__ __launch_bounds__(256) void gate_kernel(
    const float* __restrict__ xt, const float* __restrict__ gw,
    int* __restrict__ cnt, float* __restrict__ probsum,
    int* __restrict__ tok_e, float* __restrict__ tok_w)
{
    __shared__ float s_probs[4][8];
    __shared__ int   s_cnt[8];
    int tid = threadIdx.x;
    if (tid < 8) s_cnt[tid] = 0;
    __syncthreads();

    int wave = tid >> 6, lane = tid & 63;
    int t = blockIdx.x * 4 + wave;

    float acc[8];
#pragma unroll
    for (int e = 0; e < 8; e++) acc[e] = 0.f;
    const float* xrow = xt + (size_t)t * H_DIM;
    for (int k = lane; k < H_DIM; k += 64) {
        float xv = xrow[k];
#pragma unroll
        for (int e = 0; e < 8; e++) acc[e] = fmaf(xv, gw[e * H_DIM + k], acc[e]);
    }
#pragma unroll
    for (int off = 32; off > 0; off >>= 1) {
#pragma unroll
        for (int e = 0; e < 8; e++) acc[e] += __shfl_down(acc[e], off);
    }
    if (lane == 0) {
        float mx = acc[0];
#pragma unroll
        for (int e = 1; e < 8; e++) mx = fmaxf(mx, acc[e]);
        float p[8]; float sum = 0.f;
#pragma unroll
        for (int e = 0; e < 8; e++) { p[e] = expf(acc[e] - mx); sum += p[e]; }
        float inv = 1.f / sum;
#pragma unroll
        for (int e = 0; e < 8; e++) p[e] *= inv;
        int i0 = 0;
#pragma unroll
        for (int e = 1; e < 8; e++) if (p[e] > p[i0]) i0 = e;
        int i1 = (i0 == 0) ? 1 : 0;
#pragma unroll
        for (int e = 0; e < 8; e++) if (e != i0 && p[e] > p[i1]) i1 = e;
        float w0 = p[i0], w1v = p[i1];
        float denom = w0 + w1v + 1e-6f;
        tok_e[t * 2 + 0] = i0;            tok_e[t * 2 + 1] = i1;
        tok_w[t * 2 + 0] = w0 / denom;    tok_w[t * 2 + 1] = w1v / denom;
        atomicAdd(&s_cnt[i0], 1);
        atomicAdd(&s_cnt[i1], 1);
#pragma unroll
        for (int e = 0; e < 8; e++) s_probs[wave][e] = p[e];
    }
    __syncthreads();
    if (tid < 8) {
        float s = s_probs[0][tid] + s_probs[1][tid] + s_probs[2][tid] + s_probs[3][tid];
        atomicAdd(&probsum[tid], s);
        if (s_cnt[tid]) atomicAdd(&cnt[tid], s_cnt[tid]);
    }
}

__global__ void offs_aux_kernel(const int* __restrict__ cnt,
                                const float* __restrict__ probsum,
                                int* __restrict__ offs, int* __restrict__ cursor,
                                float* __restrict__ out_aux)
{
    if (threadIdx.x == 0 && blockIdx.x == 0) {
        int o = 0; float aux = 0.f;
        for (int e = 0; e < E_EXP; e++) {
            offs[e] = o; cursor[e] = o; o += cnt[e];
            aux += (float)cnt[e] * probsum[e];
        }
        out_aux[0] = aux * (float)E_EXP / ((float)T_TOK * (float)T_TOK);
    }
}

__global__ __launch_bounds__(256) void scatter_kernel(
    const int* __restrict__ tok_e, const float* __restrict__ tok_w,
    int* __restrict__ cursor, int* __restrict__ idx_list, float* __restrict__ wgt_list)
{
    int t = blockIdx.x * 256 + threadIdx.x;
#pragma unroll
    for (int s = 0; s < K_TOP; s++) {
        int e = tok_e[t * 2 + s];
        int pos = atomicAdd(&cursor[e], 1);
        idx_list[pos] = t;
        wgt_list[pos] = tok_w[t * 2 + s];
    }
}

__global__ __launch_bounds__(256) void convert_split_kernel(
    const float4* __restrict__ src, uint4* __restrict__ hi, uint4* __restrict__ lo,
    int nchunk)
{
    int stride = gridDim.x * blockDim.x;
    for (int c = blockIdx.x * blockDim.x + threadIdx.x; c < nchunk; c += stride) {
        float4 a = src[2 * c + 0];
        float4 b = src[2 * c + 1];
        unsigned h[4], l[4];
        split4(a, &h[0], &l[0]);
        split4(b, &h[2], &l[2]);
        hi[c] = make_uint4(h[0], h[1], h[2], h[3]);
        lo[c] = make_uint4(l[0], l[1], l[2], l[3]);
    }
}

// ---------------------------------------------------------------------------
// PS GEMM1 (2-phase, global_load_lds DMA staging): tile 128x64, BK=32, 4 waves
// ---------------------------------------------------------------------------
__global__ __launch_bounds__(256) void gemm1_ps(
    const unsigned short* __restrict__ xh, const unsigned short* __restrict__ xl,
    const unsigned short* __restrict__ w1h, const unsigned short* __restrict__ w1l,
    const unsigned short* __restrict__ w3h, const unsigned short* __restrict__ w3l,
    const int* __restrict__ cnt, const int* __restrict__ offs,
    const int* __restrict__ idx_list,
    unsigned short* __restrict__ hdnh, unsigned short* __restrict__ hdnl, int ebase)
{
    int z = blockIdx.z;
    int e = ebase + z;
    int n_e = cnt[e];
    int row0 = blockIdx.y * 128;
    if (row0 >= n_e) return;
    int col0 = blockIdx.x * 64;
    int lbase = offs[e];

    __shared__ __align__(16) unsigned short Ah[2][128 * 32], Al[2][128 * 32];
    __shared__ __align__(16) unsigned short B1h[2][64 * 32], B1l[2][64 * 32];
    __shared__ __align__(16) unsigned short B3h[2][64 * 32], B3l[2][64 * 32];
    __shared__ int toks[128];

    int tid = threadIdx.x;
    if (tid < 128) {
        int r = row0 + tid;
        toks[tid] = (r < n_e) ? idx_list[lbase + r] : -1;
    }
    __syncthreads();

    const size_t wbase = (size_t)z * I_DIM * H_DIM;
    int lane = tid & 63, wid = tid >> 6;

    // ---- staging descriptors: 8 DMA slots/wave, 64 chunks (1KB) each ----
    // slots 0-3: A (planes xh,xl; 512 chunks each); slots 4-7: B (4 planes x 256)
    const unsigned short* gp[8];
    unsigned short* lp[8];
    int lstr[8];
#pragma unroll
    for (int s = 0; s < 8; ++s) {
        if (s < 4) {
            int g = s * 4 + wid;                 // 0..15
            int plane = g >> 3;                  // 0:h 1:l
            int cp = ((g & 7) << 6) + lane;      // 0..511
            int r, kc; dec_swz(cp, r, kc);
            int tok = toks[r]; if (tok < 0) tok = 0;
            gp[s] = (plane ? xl : xh) + (size_t)tok * H_DIM + kc * 8;
            lp[s] = (plane ? &Al[0][0] : &Ah[0][0]) + ((g & 7) << 9);
            lstr[s] = 128 * 32;
        } else {
            int g = (s - 4) * 4 + wid;           // 0..15
            int plane = g >> 2;                  // 0..3: B1h,B1l,B3h,B3l
            int cp = ((g & 3) << 6) + lane;      // 0..255
            int r, kc; dec_swz(cp, r, kc);
            size_t src = wbase + (size_t)(col0 + r) * H_DIM + kc * 8;
            gp[s] = (plane == 0 ? w1h : plane == 1 ? w1l : plane == 2 ? w3h : w3l) + src;
            lp[s] = (plane == 0 ? &B1h[0][0] : plane == 1 ? &B1l[0][0]
                     : plane == 2 ? &B3h[0][0] : &B3l[0][0]) + ((g & 3) << 9);
            lstr[s] = 64 * 32;
        }
    }

    auto STAGE = [&](int b, int k0) {
#pragma unroll
        for (int s = 0; s < 8; ++s)
            GLOAD16(gp[s] + k0, lp[s] + b * lstr[s]);
    };

    f32x4 accu[4][2], accv[4][2];
#pragma unroll
    for (int i = 0; i < 4; i++)
#pragma unroll
        for (int j = 0; j < 2; j++) { accu[i][j] = (f32x4)(0.f); accv[i][j] = (f32x4)(0.f); }

    int wm = wid >> 1, wn = wid & 1;
    int lr = lane & 15, lq = lane >> 4;

    const int NT = H_DIM / 32;
    STAGE(0, 0);
    __syncthreads();    // drains vmcnt: buf0 ready

    for (int t = 0; t < NT; ++t) {
        int cur = t & 1;
        if (t + 1 < NT) STAGE(cur ^ 1, (t + 1) * 32);

        bf16x8 ah[4], al[4];
#pragma unroll
        for (int i = 0; i < 4; i++) {
            int r = wm * 64 + i * 16 + lr;
            int s = SWZ(r, lq * 8);
            ah[i] = *(const bf16x8*)&Ah[cur][s];
            al[i] = *(const bf16x8*)&Al[cur][s];
        }
#pragma unroll
        for (int j = 0; j < 2; j++) {
            int rb = wn * 32 + j * 16 + lr;
            int s = SWZ(rb, lq * 8);
            bf16x8 b1h = *(const bf16x8*)&B1h[cur][s];
            bf16x8 b1l = *(const bf16x8*)&B1l[cur][s];
            bf16x8 b3h = *(const bf16x8*)&B3h[cur][s];
            bf16x8 b3l = *(const bf16x8*)&B3l[cur][s];
#pragma unroll
            for (int i = 0; i < 4; i++) {
                accu[i][j] = MFMA16(ah[i], b1h, accu[i][j]);
                accu[i][j] = MFMA16(ah[i], b1l, accu[i][j]);
                accu[i][j] = MFMA16(al[i], b1h, accu[i][j]);
                accv[i][j] = MFMA16(ah[i], b3h, accv[i][j]);
                accv[i][j] = MFMA16(ah[i], b3l, accv[i][j]);
                accv[i][j] = MFMA16(al[i], b3h, accv[i][j]);
            }
        }
        __syncthreads();    // drains vmcnt (next buf landed) + lgkm
    }

#pragma unroll
    for (int i = 0; i < 4; i++) {
#pragma unroll
        for (int r = 0; r < 4; r++) {
            int lrow = wm * 64 + i * 16 + lq * 4 + r;
            int grow = row0 + lrow;
            if (grow < n_e) {
                size_t base = (size_t)(lbase + grow) * I_DIM + col0;
#pragma unroll
                for (int j = 0; j < 2; j++) {
                    float u = accu[i][j][r], v = accv[i][j][r];
                    float si = u / (1.f + expf(-u));
                    float val = si * v;
                    unsigned short h = f2bf(val);
                    unsigned short l = f2bf(val - bf2f(h));
                    int cidx = wn * 32 + j * 16 + lr;
                    hdnh[base + cidx] = h;
                    hdnl[base + cidx] = l;
                }
            }
        }
    }
}

// ---------------------------------------------------------------------------
// PS GEMM2 (2-phase, DMA staging): tile 128x128 over H, BK=32, 4 waves 2x2
// ---------------------------------------------------------------------------
__global__ __launch_bounds__(256) void gemm2_ps(
    const unsigned short* __restrict__ hdnh, const unsigned short* __restrict__ hdnl,
    const unsigned short* __restrict__ w2h, const unsigned short* __restrict__ w2l,
    const int* __restrict__ cnt, const int* __restrict__ offs,
    const int* __restrict__ idx_list, const float* __restrict__ wgt_list,
    float* __restrict__ out, int ebase)
{
    int z = blockIdx.z;
    int e = ebase + z;
    int n_e = cnt[e];
    int row0 = blockIdx.y * 128;
    if (row0 >= n_e) return;
    int col0 = blockIdx.x * 128;
    int lbase = offs[e];

    __shared__ __align__(16) unsigned short Ah2[2][128 * 32], Al2[2][128 * 32];
    __shared__ __align__(16) unsigned short Bh2[2][128 * 32], Bl2[2][128 * 32];
    __shared__ int   s_tok[128];
    __shared__ float s_wgt[128];

    int tid = threadIdx.x;
    if (tid < 128) {
        int r = row0 + tid;
        s_tok[tid] = (r < n_e) ? idx_list[lbase + r] : -1;
        s_wgt[tid] = (r < n_e) ? wgt_list[lbase + r] : 0.f;
    }
    __syncthreads();

    const size_t wbase = (size_t)z * H_DIM * I_DIM;
    int lane = tid & 63, wid = tid >> 6;

    // slots 0-3: A (hdnh,hdnl; 512 chunks each); slots 4-7: B (w2h,w2l; 512 each)
    const unsigned short* gp[8];
    unsigned short* lp[8];
#pragma unroll
    for (int s = 0; s < 8; ++s) {
        int g = (s & 3) * 4 + wid;               // 0..15
        int plane = g >> 3;                      // 0:h 1:l
        int cp = ((g & 7) << 6) + lane;          // 0..511
        int r, kc; dec_swz(cp, r, kc);
        if (s < 4) {
            int ar = row0 + r; if (ar >= n_e) ar = n_e - 1;   // clamp: rows unused anyway
            gp[s] = (plane ? hdnl : hdnh) + (size_t)(lbase + ar) * I_DIM + kc * 8;
            lp[s] = (plane ? &Al2[0][0] : &Ah2[0][0]) + ((g & 7) << 9);
        } else {
            gp[s] = (plane ? w2l : w2h) + wbase + (size_t)(col0 + r) * I_DIM + kc * 8;
            lp[s] = (plane ? &Bl2[0][0] : &Bh2[0][0]) + ((g & 7) << 9);
        }
    }

    auto STAGE = [&](int b, int k0) {
#pragma unroll
        for (int s = 0; s < 8; ++s)
            GLOAD16(gp[s] + k0, lp[s] + b * (128 * 32));
    };

    f32x4 acc[4][4];
#pragma unroll
    for (int i = 0; i < 4; i++)
#pragma unroll
        for (int j = 0; j < 4; j++) acc[i][j] = (f32x4)(0.f);

    int wm = wid >> 1, wn = wid & 1;
    int lr = lane & 15, lq = lane >> 4;

    const int NT = I_DIM / 32;
    STAGE(0, 0);
    __syncthreads();

    for (int t = 0; t < NT; ++t) {
        int cur = t & 1;
        if (t + 1 < NT) STAGE(cur ^ 1, (t + 1) * 32);

        bf16x8 ah[4], al[4];
#pragma unroll
        for (int i = 0; i < 4; i++) {
            int r = wm * 64 + i * 16 + lr;
            int s = SWZ(r, lq * 8);
            ah[i] = *(const bf16x8*)&Ah2[cur][s];
            al[i] = *(const bf16x8*)&Al2[cur][s];
        }
#pragma unroll
        for (int j = 0; j < 4; j++) {
            int rb = wn * 64 + j * 16 + lr;
            int s = SWZ(rb, lq * 8);
            bf16x8 bh = *(const bf16x8*)&Bh2[cur][s];
            bf16x8 bl = *(const bf16x8*)&Bl2[cur][s];
#pragma unroll
            for (int i = 0; i < 4; i++) {
                acc[i][j] = MFMA16(ah[i], bh, acc[i][j]);
                acc[i][j] = MFMA16(ah[i], bl, acc[i][j]);
                acc[i][j] = MFMA16(al[i], bh, acc[i][j]);
            }
        }
        __syncthreads();
    }

#pragma unroll
    for (int i = 0; i < 4; i++) {
#pragma unroll
        for (int r = 0; r < 4; r++) {
            int lrow = wm * 64 + i * 16 + lq * 4 + r;
            int grow = row0 + lrow;
            if (grow < n_e) {
                int t = s_tok[lrow];
                float wt = s_wgt[lrow];
                float* orow = out + (size_t)t * H_DIM + col0;
#pragma unroll
                for (int j = 0; j < 4; j++)
                    atomicAdd(&orow[wn * 64 + j * 16 + lr], wt * acc[i][j][r]);
            }
        }
    }
}

// ---------------------------------------------------------------------------
// Fallback (single-buffer, on-the-fly split, fp32 hdn) — used only if ws tiny
// ---------------------------------------------------------------------------
__global__ __launch_bounds__(256) void gemm1_mfma(
    const float* __restrict__ xt, const float* __restrict__ w1,
    const float* __restrict__ w3,
    const int* __restrict__ cnt, const int* __restrict__ offs,
    const int* __restrict__ idx_list,
    float* __restrict__ hdn, int e_param, int compact)
{
    int e = (e_param >= 0) ? e_param : (int)blockIdx.z;
    int n_e = cnt[e];
    int row0 = blockIdx.y * 128;
    if (row0 >= n_e) return;
    int col0 = blockIdx.x * 64;
    int lbase = offs[e];
    size_t hbase = compact ? (size_t)lbase : 0;

    __shared__ unsigned short Ah[128 * 32], Al[128 * 32];
    __shared__ unsigned short B1h[64 * 32], B1l[64 * 32];
    __shared__ unsigned short B3h[64 * 32], B3l[64 * 32];
    __shared__ int toks[128];

    int tid = threadIdx.x;
    if (tid < 128) {
        int r = row0 + tid;
        toks[tid] = (r < n_e) ? idx_list[lbase + r] : -1;
    }
    __syncthreads();

    const float* w1e = w1 + (size_t)e * I_DIM * H_DIM;
    const float* w3e = w3 + (size_t)e * I_DIM * H_DIM;

    f32x4 accu[4][2], accv[4][2];
#pragma unroll
    for (int i = 0; i < 4; i++)
#pragma unroll
        for (int j = 0; j < 2; j++) { accu[i][j] = (f32x4)(0.f); accv[i][j] = (f32x4)(0.f); }

    int lane = tid & 63, wid = tid >> 6;
    int wm = wid >> 1, wn = wid & 1;
    int lr = lane & 15, lq = lane >> 4;

    for (int k0 = 0; k0 < H_DIM; k0 += 32) {
#pragma unroll
        for (int p = 0; p < 4; p++) {
            int idx = tid + p * 256;
            int row = idx >> 3, kq = (idx & 7) << 2;
            int tok = toks[row];
            float4 v = (tok >= 0)
                ? *(const float4*)&xt[(size_t)tok * H_DIM + k0 + kq]
                : make_float4(0.f, 0.f, 0.f, 0.f);
            unsigned hi[2], lo[2];
            split4(v, hi, lo);
            int s = SWZ(row, kq);
            *(uint2*)&Ah[s] = make_uint2(hi[0], hi[1]);
            *(uint2*)&Al[s] = make_uint2(lo[0], lo[1]);
        }
#pragma unroll
        for (int p = 0; p < 2; p++) {
            int idx = tid + p * 256;
            int row = idx >> 3, kq = (idx & 7) << 2;
            size_t goff = (size_t)(col0 + row) * H_DIM + k0 + kq;
            float4 v1 = *(const float4*)&w1e[goff];
            float4 v3 = *(const float4*)&w3e[goff];
            unsigned hi[2], lo[2];
            int s = SWZ(row, kq);
            split4(v1, hi, lo);
            *(uint2*)&B1h[s] = make_uint2(hi[0], hi[1]);
            *(uint2*)&B1l[s] = make_uint2(lo[0], lo[1]);
            split4(v3, hi, lo);
            *(uint2*)&B3h[s] = make_uint2(hi[0], hi[1]);
            *(uint2*)&B3l[s] = make_uint2(lo[0], lo[1]);
        }
        __syncthreads();

        bf16x8 ah[4], al[4];
#pragma unroll
        for (int i = 0; i < 4; i++) {
            int r = wm * 64 + i * 16 + lr;
            int s = SWZ(r, lq * 8);
            ah[i] = *(const bf16x8*)&Ah[s];
            al[i] = *(const bf16x8*)&Al[s];
        }
#pragma unroll
        for (int j = 0; j < 2; j++) {
            int rb = wn * 32 + j * 16 + lr;
            int s = SWZ(rb, lq * 8);
            bf16x8 b1h = *(const bf16x8*)&B1h[s];
            bf16x8 b1l = *(const bf16x8*)&B1l[s];
            bf16x8 b3h = *(const bf16x8*)&B3h[s];
            bf16x8 b3l = *(const bf16x8*)&B3l[s];
#pragma unroll
            for (int i = 0; i < 4; i++) {
                accu[i][j] = MFMA16(ah[i], b1h, accu[i][j]);
                accu[i][j] = MFMA16(ah[i], b1l, accu[i][j]);
                accu[i][j] = MFMA16(al[i], b1h, accu[i][j]);
                accv[i][j] = MFMA16(ah[i], b3h, accv[i][j]);
                accv[i][j] = MFMA16(ah[i], b3l, accv[i][j]);
                accv[i][j] = MFMA16(al[i], b3h, accv[i][j]);
            }
        }
        __syncthreads();
    }

#pragma unroll
    for (int i = 0; i < 4; i++) {
#pragma unroll
        for (int r = 0; r < 4; r++) {
            int lrow = wm * 64 + i * 16 + lq * 4 + r;
            int grow = row0 + lrow;
            if (grow < n_e) {
                float* hrow = hdn + (hbase + grow) * (size_t)I_DIM + col0;
#pragma unroll
                for (int j = 0; j < 2; j++) {
                    float u = accu[i][j][r];
                    float v = accv[i][j][r];
                    float si = u / (1.f + expf(-u));
                    hrow[wn * 32 + j * 16 + lr] = si * v;
                }
            }
        }
    }
}

__global__ __launch_bounds__(256) void gemm2_mfma(
    const float* __restrict__ hdn, const float* __restrict__ w2,
    const int* __restrict__ cnt, const int* __restrict__ offs,
    const int* __restrict__ idx_list, const float* __restrict__ wgt_list,
    float* __restrict__ out, int e_param, int compact)
{
    int e = (e_param >= 0) ? e_param : (int)blockIdx.z;
    int n_e = cnt[e];
    int row0 = blockIdx.y * 128;
    if (row0 >= n_e) return;
    int col0 = blockIdx.x * 128;
    int lbase = offs[e];
    size_t hbase = compact ? (size_t)lbase : 0;

    __shared__ unsigned short Ah[128 * 32], Al[128 * 32];
    __shared__ unsigned short Bh[128 * 32], Bl[128 * 32];
    __shared__ int   s_tok[128];
    __shared__ float s_wgt[128];

    int tid = threadIdx.x;
    if (tid < 128) {
        int r = row0 + tid;
        s_tok[tid] = (r < n_e) ? idx_list[lbase + r] : -1;
        s_wgt[tid] = (r < n_e) ? wgt_list[lbase + r] : 0.f;
    }

    const float* w2e = w2 + (size_t)e * H_DIM * I_DIM;

    f32x4 acc[4][4];
#pragma unroll
    for (int i = 0; i < 4; i++)
#pragma unroll
        for (int j = 0; j < 4; j++) acc[i][j] = (f32x4)(0.f);

    int lane = tid & 63, wid = tid >> 6;
    int wm = wid >> 1, wn = wid & 1;
    int lr = lane & 15, lq = lane >> 4;

    for (int k0 = 0; k0 < I_DIM; k0 += 32) {
#pragma unroll
        for (int p = 0; p < 4; p++) {
            int idx = tid + p * 256;
            int row = idx >> 3, kq = (idx & 7) << 2;
            float4 v = (row0 + row < n_e)
                ? *(const float4*)&hdn[(hbase + row0 + row) * (size_t)I_DIM + k0 + kq]
                : make_float4(0.f, 0.f, 0.f, 0.f);
            unsigned hi[2], lo[2];
            split4(v, hi, lo);
            int s = SWZ(row, kq);
            *(uint2*)&Ah[s] = make_uint2(hi[0], hi[1]);
            *(uint2*)&Al[s] = make_uint2(lo[0], lo[1]);
        }
#pragma unroll
        for (int p = 0; p < 4; p++) {
            int idx = tid + p * 256;
            int row = idx >> 3, kq = (idx & 7) << 2;
            float4 v = *(const float4*)&w2e[(size_t)(col0 + row) * I_DIM + k0 + kq];
            unsigned hi[2], lo[2];
            split4(v, hi, lo);
            int s = SWZ(row, kq);
            *(uint2*)&Bh[s] = make_uint2(hi[0], hi[1]);
            *(uint2*)&Bl[s] = make_uint2(lo[0], lo[1]);
        }
        __syncthreads();

        bf16x8 ah[4], al[4];
#pragma unroll
        for (int i = 0; i < 4; i++) {
            int r = wm * 64 + i * 16 + lr;
            int s = SWZ(r, lq * 8);
            ah[i] = *(const bf16x8*)&Ah[s];
            al[i] = *(const bf16x8*)&Al[s];
        }
#pragma unroll
        for (int j = 0; j < 4; j++) {
            int rb = wn * 64 + j * 16 + lr;
            int s = SWZ(rb, lq * 8);
            bf16x8 bh = *(const bf16x8*)&Bh[s];
            bf16x8 bl = *(const bf16x8*)&Bl[s];
#pragma unroll
            for (int i = 0; i < 4; i++) {
                acc[i][j] = MFMA16(ah[i], bh, acc[i][j]);
                acc[i][j] = MFMA16(ah[i], bl, acc[i][j]);
                acc[i][j] = MFMA16(al[i], bh, acc[i][j]);
            }
        }
        __syncthreads();
    }

#pragma unroll
    for (int i = 0; i < 4; i++) {
#pragma unroll
        for (int r = 0; r < 4; r++) {
            int lrow = wm * 64 + i * 16 + lq * 4 + r;
            int grow = row0 + lrow;
            if (grow < n_e) {
                int t = s_tok[lrow];
                float wt = s_wgt[lrow];
                float* orow = out + (size_t)t * H_DIM + col0;
#pragma unroll
                for (int j = 0; j < 4; j++)
                    atomicAdd(&orow[wn * 64 + j * 16 + lr], wt * acc[i][j][r]);
            }
        }
    }
}

extern "C" void kernel_launch(void* const* d_in, const int* in_sizes, int n_in,
                              void* d_out, int out_size, void* d_ws, size_t ws_size,
                              hipStream_t stream) {
    const float* x  = (const float*)d_in[0];
    const float* gw = (const float*)d_in[1];
    const float* w1 = (const float*)d_in[2];
    const float* w2 = (const float*)d_in[3];
    const float* w3 = (const float*)d_in[4];
    float* out = (float*)d_out;

    char* ws = (char*)d_ws;
    int*   cnt      = (int*)(ws + 0);
    int*   cursor   = (int*)(ws + 32);
    float* probsum  = (float*)(ws + 64);
    int*   offs     = (int*)(ws + 96);
    int*   tok_e    = (int*)(ws + 256);
    float* tok_w    = (float*)(ws + 256 + 65536);
    int*   idx_list = (int*)(ws + 256 + 2 * 65536);
    float* wgt_list = (float*)(ws + 256 + 3 * 65536);
    size_t buf0     = 256 + 4 * 65536;     // 262400, 256-aligned

    const size_t XP = (size_t)T_TOK * H_DIM * 2;     // x plane: 16.78 MB
    const size_t WP = (size_t)I_DIM * H_DIM * 2;     // weight plane/expert: 4.19 MB
    const size_t DP = (size_t)T_TOK * K_TOP * I_DIM * 2;  // hdn plane: 67.1 MB

    int EG = 0;
    size_t xh_o = 0, xl_o = 0, wslot_o = 0, dh_o = 0, dl_o = 0;
    for (int eg = E_EXP; eg >= 1; eg >>= 1) {
        size_t off = buf0;
        size_t a = off; off += XP;
        size_t b = off; off += XP;
        size_t c = off; off += 4 * eg * WP;
        size_t d = off; off += DP;
        size_t f = off; off += DP;
        if (off <= ws_size) { EG = eg; xh_o = a; xl_o = b; wslot_o = c; dh_o = d; dl_o = f; break; }
    }
    size_t need1 = buf0 + (size_t)T_TOK * K_TOP * I_DIM * sizeof(float);

    hipMemsetAsync(ws, 0, 128, stream);
    hipMemsetAsync(d_out, 0, (size_t)T_TOK * H_DIM * sizeof(float), stream);

    gate_kernel<<<T_TOK / 4, 256, 0, stream>>>(x, gw, cnt, probsum, tok_e, tok_w);
    offs_aux_kernel<<<1, 64, 0, stream>>>(cnt, probsum, offs, cursor,
                                          out + (size_t)T_TOK * H_DIM);
    scatter_kernel<<<T_TOK / 256, 256, 0, stream>>>(tok_e, tok_w, cursor,
                                                    idx_list, wgt_list);

    if (EG >= 1) {
        unsigned short* xh = (unsigned short*)(ws + xh_o);
        unsigned short* xl = (unsigned short*)(ws + xl_o);
        unsigned short* dh = (unsigned short*)(ws + dh_o);
        unsigned short* dl = (unsigned short*)(ws + dl_o);
        unsigned short* s_w1h = (unsigned short*)(ws + wslot_o + 0 * EG * WP);
        unsigned short* s_w1l = (unsigned short*)(ws + wslot_o + 1 * EG * WP);
        unsigned short* s_w3h = (unsigned short*)(ws + wslot_o + 2 * EG * WP);
        unsigned short* s_w3l = (unsigned short*)(ws + wslot_o + 3 * EG * WP);
        unsigned short* s_w2h = (unsigned short*)(ws + wslot_o + 0 * EG * WP);
        unsigned short* s_w2l = (unsigned short*)(ws + wslot_o + 1 * EG * WP);

        {
            int nch = T_TOK * H_DIM / 8;
            int g = (nch + 255) / 256; if (g > 2048) g = 2048;
            convert_split_kernel<<<g, 256, 0, stream>>>(
                (const float4*)x, (uint4*)xh, (uint4*)xl, nch);
        }
        const int wch = (int)((size_t)EG * I_DIM * H_DIM / 8);
        int wg = (wch + 255) / 256; if (wg > 2048) wg = 2048;

        for (int eb = 0; eb < E_EXP; eb += EG) {
            const size_t woff = (size_t)eb * I_DIM * H_DIM;
            convert_split_kernel<<<wg, 256, 0, stream>>>(
                (const float4*)(w1 + woff), (uint4*)s_w1h, (uint4*)s_w1l, wch);
            convert_split_kernel<<<wg, 256, 0, stream>>>(
                (const float4*)(w3 + woff), (uint4*)s_w3h, (uint4*)s_w3l, wch);
            dim3 g1(I_DIM / 64, T_TOK / 128, EG);
            gemm1_ps<<<g1, 256, 0, stream>>>(xh, xl, s_w1h, s_w1l, s_w3h, s_w3l,
                                             cnt, offs, idx_list, dh, dl, eb);
            convert_split_kernel<<<wg, 256, 0, stream>>>(
                (const float4*)(w2 + woff), (uint4*)s_w2h, (uint4*)s_w2l, wch);
            dim3 g2(H_DIM / 128, T_TOK / 128, EG);
            gemm2_ps<<<g2, 256, 0, stream>>>(dh, dl, s_w2h, s_w2l,
                                             cnt, offs, idx_list, wgt_list, out, eb);
        }
    } else if (ws_size >= need1) {
        float* hdn = (float*)(ws + buf0);
        dim3 g1(I_DIM / 64, T_TOK / 128, E_EXP);
        gemm1_mfma<<<g1, 256, 0, stream>>>(x, w1, w3, cnt, offs, idx_list, hdn, -1, 1);
        dim3 g2(H_DIM / 128, T_TOK / 128, E_EXP);
        gemm2_mfma<<<g2, 256, 0, stream>>>(hdn, w2, cnt, offs, idx_list, wgt_list,
                                           out, -1, 1);
    } else {
        float* hdn = (float*)(ws + buf0);
        for (int e = 0; e < E_EXP; e++) {
            gemm1_mfma<<<dim3(I_DIM / 64, T_TOK / 128, 1), 256, 0, stream>>>(
                x, w1, w3, cnt, offs, idx_list, hdn, e, 0);
            gemm2_mfma<<<dim3(H_DIM / 128, T_TOK / 128, 1), 256, 0, stream>>>(
                hdn, w2, cnt, offs, idx_list, wgt_list, out, e, 0);
        }
    }
}